// Round 11
// baseline (185.397 us; speedup 1.0000x reference)
//
#include <hip/hip_runtime.h>
#include <hip/hip_bf16.h>

typedef __attribute__((ext_vector_type(8))) short bf16x8;
typedef __attribute__((ext_vector_type(4))) float f32x4;
typedef __attribute__((ext_vector_type(16))) float f32x16;
typedef __attribute__((ext_vector_type(4))) unsigned int u32x4;

#define BATCH 32
#define SEQ   2048
#define PSTR  20    // fallback kernel only
#define KSTR  72    // fallback kernel only
#define VSTR  36    // fallback + prepkv staging
#define LOG2E 1.44269504088896340736f
#define QSCALE (0.125f * LOG2E)
#define NEGL  (-1000000.0f * LOG2E)

__device__ __forceinline__ unsigned int pk2(float lo, float hi) {
    __hip_bfloat162 h2 = __float22bfloat162_rn(make_float2(lo, hi));  // v_cvt_pk_bf16_f32
    return *reinterpret_cast<unsigned int*>(&h2);
}

// v_permlane32_swap_b32: a[32:63] <-> b[0:31].
__device__ __forceinline__ void plswap(unsigned int& a, unsigned int& b) {
    asm volatile("v_permlane32_swap_b32 %0, %1" : "+v"(a), "+v"(b));
}

// standalone prep (fallback path only)
__global__ void prep_vl(const int* __restrict__ VL, int* __restrict__ meta) {
    __shared__ int sv[BATCH];
    const int t = threadIdx.x;
    int odd = (t < 16) ? VL[2 * t + 1] : 0;
    const bool is64 = (__ballot(odd != 0) == 0ULL);
    if (t < BATCH) {
        int x = is64 ? VL[2 * t] : VL[t];
        x = x < 0 ? 0 : (x > SEQ ? SEQ : x);
        sv[t] = x;
    }
    __syncthreads();
    if (t < BATCH) {
        const int x = sv[t];
        int rank = 0;
        for (int j = 0; j < BATCH; ++j) {
            const int y = sv[j];
            rank += (y > x) || (y == x && j < t);
        }
        meta[rank] = x;
        meta[BATCH + rank] = t;
    }
}

// FRAGMENT-MAJOR workspace (r7, verified). Each MFMA fragment of attn is a
// contiguous lane-ordered 1KB extent. Linear in the 32-key group G:
//   Kw byte off = (b*64 + G)*4096 + kf*1024 + lane*16
//   Vw byte off = (b*64 + G)*4096 + q*1024  + lane*16
// -> attn loads each fragment with ONE coalesced global_load_dwordx4,
// enabling a barrier-free main loop with any key partition across waves.
// Tiles beyond ceil64(vl[b]) are skipped. Block BATCH*32 does the rank-sort.
__global__ __launch_bounds__(256) void prepkv(const float* __restrict__ Kp,
                                              const float* __restrict__ Vp,
                                              const int* __restrict__ VL,
                                              short* __restrict__ Kw,
                                              short* __restrict__ Vw,
                                              int* __restrict__ meta) {
    __shared__ unsigned int l[64 * VSTR];
    __shared__ int sv[BATCH];
    __shared__ int svl;
    const int tid = threadIdx.x;
    if (blockIdx.x == BATCH * 32) {
        if (tid < 64) {
            int odd = (tid < 16) ? VL[2 * tid + 1] : 0;
            const bool is64 = (__ballot(odd != 0) == 0ULL);   // lens>=1
            if (tid < BATCH) {
                int x = is64 ? VL[2 * tid] : VL[tid];
                x = x < 0 ? 0 : (x > SEQ ? SEQ : x);
                sv[tid] = x;
            }
            asm volatile("s_waitcnt lgkmcnt(0)" ::: "memory");
            if (tid < BATCH) {
                const int x = sv[tid];
                int rank = 0;
                for (int j = 0; j < BATCH; ++j) {
                    const int y = sv[j];
                    rank += (y > x) || (y == x && j < tid);
                }
                meta[rank] = x;
                meta[BATCH + rank] = tid;
            }
        }
        return;
    }
    const int b = blockIdx.x >> 5, kt = blockIdx.x & 31, kb = kt * 64;
    // per-block vl: skip tiles attn never reads (kt*64 >= ceil64(vl))
    if (tid < 64) {
        int odd = (tid < 16) ? VL[2 * tid + 1] : 0;
        const bool is64 = (__ballot(odd != 0) == 0ULL);
        if (tid == 0) {
            int x = is64 ? VL[2 * b] : VL[b];
            x = x < 0 ? 0 : (x > SEQ ? SEQ : x);
            svl = x;
        }
    }
    __syncthreads();
    if (kb >= ((svl + 63) & ~63)) return;   // block-uniform exit
    const float* Kv = Kp + ((size_t)b * SEQ + kb) * 64;
    const float* Vb = Vp + ((size_t)b * SEQ + kb) * 64;
    const size_t tbase = (size_t)(b * 32 + kt) * 8192;   // bytes per tile

    // K: 512 chunks of 16B, fragment-major; writes coalesced
    #pragma unroll
    for (int h = 0; h < 2; ++h) {
        const int c = tid + h * 256;
        const int kh = c >> 8, kf = (c >> 6) & 3, ln = c & 63;
        const int key = kh * 32 + (ln & 31), col = kf * 16 + (ln >> 5) * 8;
        f32x4 a = *(const f32x4*)(Kv + key * 64 + col);
        f32x4 d = *(const f32x4*)(Kv + key * 64 + col + 4);
        u32x4 w;
        w.x = pk2(a[0], a[1]); w.y = pk2(a[2], a[3]);
        w.z = pk2(d[0], d[1]); w.w = pk2(d[2], d[3]);
        *(u32x4*)((char*)Kw + tbase + (size_t)c * 16) = w;
    }
    // V: build packed-pair transpose in LDS, then fragment-major out
    #pragma unroll
    for (int h = 0; h < 2; ++h) {
        const int u = tid + h * 256;
        const int d4 = (u & 3) + ((u >> 7) << 2);
        const int kp = (u >> 2) & 31;
        f32x4 a = *(const f32x4*)(Vb + (2 * kp) * 64 + d4 * 4);
        f32x4 c = *(const f32x4*)(Vb + (2 * kp + 1) * 64 + d4 * 4);
        #pragma unroll
        for (int j = 0; j < 4; ++j)
            l[(d4 * 4 + j) * VSTR + kp] = pk2(a[j], c[j]);
    }
    __syncthreads();
    #pragma unroll
    for (int h = 0; h < 2; ++h) {
        const int cV = tid + h * 256;
        const int kh = cV >> 8, q = (cV >> 6) & 3, ln = cV & 63;
        const int d = (q >> 1) * 32 + (ln & 31);
        const int cc = kh * 4 + (q & 1) * 2 + (ln >> 5);
        u32x4 w = *(const u32x4*)&l[d * VSTR + 4 * cc];
        *(u32x4*)((char*)Vw + tbase + (size_t)cV * 16) = w;
    }
}

// ---- main: round-11 = r10 (verified: XCD-affine, barrier-free, FETCH at
// compulsory 12.5MB) + PREFETCH DEPTH 2. r10 post-mortem: L2-affinity fixed
// traffic but dur invariant -> per-SIMD issue only ~18k of 103k cyc (82%
// stall); the shared term across all structures is depth-1 prefetch: load-to-
// use gap (~250-300 cyc of issue) < L2-under-load latency (300-500 cyc), so
// every tile stalls on vmcnt twice. Fix: double-buffered fragment registers
// (kkA/B, vvA/B, named -> static indexing per rule #20), loop unrolled x2;
// tile t issues loads for t+2 right after consuming its fragments -> gap
// ~1.5 tiles (600-900 cyc). Cost +32 VGPR (~112); occupancy proven NOT
// binding (r9: 2x waves = null), so the reg growth is acceptable. ----
__global__ __launch_bounds__(512, 4)
void attn_fwd(const float* __restrict__ Qp, const short* __restrict__ Kw,
              const short* __restrict__ Vw, const int* __restrict__ meta,
              float* __restrict__ Out) {
    constexpr int S = SEQ;
    __shared__ float mA[2 * 2048];   // 16 KB merge buffer A
    __shared__ float mB[2 * 2048];   // 16 KB merge buffer B
    __shared__ float lA[128], lB[128];

    const int tid  = threadIdx.x;
    const int wave = tid >> 6, lane = tid & 63;
    const int r31 = lane & 31, hi = lane >> 5;
    const int qh = wave >> 2, kh = wave & 3;   // q-half, key-quarter (mod-4 groups)

    // XCD-affine decode: x = XCD (blockIdx%8 round-robin); XCD x owns slots
    // {x,15-x,16+x,31-x} (balanced rank sums); all 32 qt-blocks of a slot
    // share one XCD -> per-XCD working set 2MB <= 4MB L2 (r10: FETCH 12.5MB).
    const int x  = blockIdx.x & 7;
    const int i  = blockIdx.x >> 3;
    const int ss = i >> 5;
    const int qt = i & 31;
    const int slot = (ss == 0) ? x : (ss == 1) ? 15 - x : (ss == 2) ? 16 + x : 31 - x;

    const int vl = meta[slot], batch = meta[BATCH + slot];
    const int nG = (vl + 31) >> 5;                       // 32-key groups
    const int ntw = (nG > kh) ? ((nG - kh + 3) >> 2) : 0;  // this wave's groups

    // fragment base pointers: group G at byte (batch*64+G)*4096; stride/step 16384
    const char* kw = (const char*)Kw + ((size_t)batch * 64 + kh) * 4096 + lane * 16;
    const char* vw = (const char*)Vw + ((size_t)batch * 64 + kh) * 4096 + lane * 16;

    // Q B-fragments: lane holds Q[qh*32+r31][kf*16+hi*8+j], scale folded
    // (scores exit MFMA in log2 domain)
    bf16x8 qf[4];
    {
        const float* qb = Qp + ((size_t)batch * S + qt * 64 + qh * 32 + r31) * 64 + hi * 8;
        #pragma unroll
        for (int kf = 0; kf < 4; ++kf) {
            f32x4 a = *(const f32x4*)(qb + kf * 16);
            f32x4 c = *(const f32x4*)(qb + kf * 16 + 4);
            union { bf16x8 v; unsigned int u[4]; } qq;
            qq.u[0] = pk2(a[0] * QSCALE, a[1] * QSCALE);
            qq.u[1] = pk2(a[2] * QSCALE, a[3] * QSCALE);
            qq.u[2] = pk2(c[0] * QSCALE, c[1] * QSCALE);
            qq.u[3] = pk2(c[2] * QSCALE, c[3] * QSCALE);
            qf[kf] = qq.v;
        }
    }

    f32x16 o0, o1, zv;
    #pragma unroll
    for (int r = 0; r < 16; ++r) { o0[r] = 0.f; o1[r] = 0.f; zv[r] = 0.f; }
    float lpart = 0.f;

    // depth-2 fragment double buffer (named regs -> static indexing)
    bf16x8 kA0, kA1, kA2, kA3, vA0, vA1, vA2, vA3;   // tiles t (even)
    bf16x8 kB0, kB1, kB2, kB3, vB0, vB1, vB2, vB3;   // tiles t (odd)
    if (ntw > 0) {
        kA0 = *(const bf16x8*)(kw);
        kA1 = *(const bf16x8*)(kw + 1024);
        kA2 = *(const bf16x8*)(kw + 2048);
        kA3 = *(const bf16x8*)(kw + 3072);
        vA0 = *(const bf16x8*)(vw);
        vA1 = *(const bf16x8*)(vw + 1024);
        vA2 = *(const bf16x8*)(vw + 2048);
        vA3 = *(const bf16x8*)(vw + 3072);
    }
    if (ntw > 1) {
        const char* pk = kw + 16384;
        const char* pv = vw + 16384;
        kB0 = *(const bf16x8*)(pk);
        kB1 = *(const bf16x8*)(pk + 1024);
        kB2 = *(const bf16x8*)(pk + 2048);
        kB3 = *(const bf16x8*)(pk + 3072);
        vB0 = *(const bf16x8*)(pv);
        vB1 = *(const bf16x8*)(pv + 1024);
        vB2 = *(const bf16x8*)(pv + 2048);
        vB3 = *(const bf16x8*)(pv + 3072);
    }

    // one tile: compute with (K0..3,V0..3); after consuming each operand set,
    // immediately issue its reload for tile T+2 (gap ~1.5 tiles before use)
#define ATTN_TILE(K0, K1, K2, K3, V0, V1, V2, V3, T)                             \
    {                                                                            \
        f32x16 st;                                                               \
        __builtin_amdgcn_s_setprio(1);                                           \
        st = __builtin_amdgcn_mfma_f32_32x32x16_bf16(K0, qf[0], zv, 0, 0, 0);    \
        st = __builtin_amdgcn_mfma_f32_32x32x16_bf16(K1, qf[1], st, 0, 0, 0);    \
        st = __builtin_amdgcn_mfma_f32_32x32x16_bf16(K2, qf[2], st, 0, 0, 0);    \
        st = __builtin_amdgcn_mfma_f32_32x32x16_bf16(K3, qf[3], st, 0, 0, 0);    \
        __builtin_amdgcn_s_setprio(0);                                           \
        if ((T) + 2 < ntw) {                                                     \
            const char* p = kw + (size_t)((T) + 2) * 16384;                      \
            K0 = *(const bf16x8*)(p);                                            \
            K1 = *(const bf16x8*)(p + 1024);                                     \
            K2 = *(const bf16x8*)(p + 2048);                                     \
            K3 = *(const bf16x8*)(p + 3072);                                     \
        }                                                                        \
        const int rem = vl - (kh + 4 * (T)) * 32;                                \
        if (rem < 32) {                                                          \
            _Pragma("unroll")                                                    \
            for (int r = 0; r < 16; ++r) {                                       \
                const int kl = 4 * hi + (r & 3) + 8 * (r >> 2);                  \
                st[r] = (kl < rem) ? st[r] : NEGL;                               \
            }                                                                    \
        }                                                                        \
        _Pragma("unroll")                                                        \
        for (int r = 0; r < 16; ++r) st[r] = __builtin_amdgcn_exp2f(st[r]);      \
        {                                                                        \
            const float a0 = (st[0] + st[1]) + (st[2] + st[3]);                  \
            const float a1 = (st[4] + st[5]) + (st[6] + st[7]);                  \
            const float a2 = (st[8] + st[9]) + (st[10] + st[11]);                \
            const float a3 = (st[12] + st[13]) + (st[14] + st[15]);              \
            lpart += (a0 + a1) + (a2 + a3);                                      \
        }                                                                        \
        union { bf16x8 v; unsigned int u[4]; } pf0, pf1;                         \
        {                                                                        \
            unsigned int x0 = pk2(st[0], st[1]),   y0 = pk2(st[4], st[5]);       \
            unsigned int x1 = pk2(st[2], st[3]),   y1 = pk2(st[6], st[7]);       \
            plswap(x0, y0); plswap(x1, y1);                                      \
            pf0.u[0] = x0; pf0.u[1] = x1; pf0.u[2] = y0; pf0.u[3] = y1;          \
            unsigned int x2 = pk2(st[8], st[9]),   y2 = pk2(st[12], st[13]);     \
            unsigned int x3 = pk2(st[10], st[11]), y3 = pk2(st[14], st[15]);     \
            plswap(x2, y2); plswap(x3, y3);                                      \
            pf1.u[0] = x2; pf1.u[1] = x3; pf1.u[2] = y2; pf1.u[3] = y3;          \
        }                                                                        \
        __builtin_amdgcn_s_setprio(1);                                           \
        o0 = __builtin_amdgcn_mfma_f32_32x32x16_bf16(V0, pf0.v, o0, 0, 0, 0);    \
        o0 = __builtin_amdgcn_mfma_f32_32x32x16_bf16(V1, pf1.v, o0, 0, 0, 0);    \
        o1 = __builtin_amdgcn_mfma_f32_32x32x16_bf16(V2, pf0.v, o1, 0, 0, 0);    \
        o1 = __builtin_amdgcn_mfma_f32_32x32x16_bf16(V3, pf1.v, o1, 0, 0, 0);    \
        __builtin_amdgcn_s_setprio(0);                                           \
        if ((T) + 2 < ntw) {                                                     \
            const char* p = vw + (size_t)((T) + 2) * 16384;                      \
            V0 = *(const bf16x8*)(p);                                            \
            V1 = *(const bf16x8*)(p + 1024);                                     \
            V2 = *(const bf16x8*)(p + 2048);                                     \
            V3 = *(const bf16x8*)(p + 3072);                                     \
        }                                                                        \
    }

    for (int t = 0; t < ntw; t += 2) {
        ATTN_TILE(kA0, kA1, kA2, kA3, vA0, vA1, vA2, vA3, t);
        if (t + 1 < ntw)
            ATTN_TILE(kB0, kB1, kB2, kB3, vB0, vB1, vB2, vB3, t + 1);
    }
#undef ATTN_TILE

    // per-(q, key-quarter) l: lanes l and l+32 hold complementary row sets
    float lw = lpart + __shfl_xor(lpart, 32);

    // 4-way kh merge: (1,3 -> A,B) -> (0+=A, 2+=B) -> (2 -> A) -> (0+=A)
    if (kh == 1 || kh == 3) {
        float* m = (kh == 1) ? mA : mB;
        float* lv = (kh == 1) ? lA : lB;
        #pragma unroll
        for (int r = 0; r < 16; ++r) m[qh * 2048 + r * 64 + lane] = o0[r];
        #pragma unroll
        for (int r = 0; r < 16; ++r) m[qh * 2048 + (16 + r) * 64 + lane] = o1[r];
        lv[qh * 64 + lane] = lw;
    }
    __syncthreads();
    if (kh == 0 || kh == 2) {
        const float* m = (kh == 0) ? mA : mB;
        const float* lv = (kh == 0) ? lA : lB;
        #pragma unroll
        for (int r = 0; r < 16; ++r) o0[r] += m[qh * 2048 + r * 64 + lane];
        #pragma unroll
        for (int r = 0; r < 16; ++r) o1[r] += m[qh * 2048 + (16 + r) * 64 + lane];
        lw += lv[qh * 64 + lane];
    }
    __syncthreads();
    if (kh == 2) {
        #pragma unroll
        for (int r = 0; r < 16; ++r) mA[qh * 2048 + r * 64 + lane] = o0[r];
        #pragma unroll
        for (int r = 0; r < 16; ++r) mA[qh * 2048 + (16 + r) * 64 + lane] = o1[r];
        lA[qh * 64 + lane] = lw;
    }
    __syncthreads();
    if (kh == 0) {
        #pragma unroll
        for (int r = 0; r < 16; ++r) o0[r] += mA[qh * 2048 + r * 64 + lane];
        #pragma unroll
        for (int r = 0; r < 16; ++r) o1[r] += mA[qh * 2048 + (16 + r) * 64 + lane];
        lw += lA[qh * 64 + lane];
        const float inv = (lw > 0.f) ? 1.0f / lw : 0.f;
        const size_t orow = ((size_t)batch * S + qt * 64 + qh * 32 + r31) * 64;
        #pragma unroll
        for (int g4 = 0; g4 < 4; ++g4) {
            f32x4 w;
            #pragma unroll
            for (int j = 0; j < 4; ++j) w[j] = o0[g4 * 4 + j] * inv;
            *(f32x4*)(Out + orow + g4 * 8 + hi * 4) = w;
        }
        #pragma unroll
        for (int g4 = 0; g4 < 4; ++g4) {
            f32x4 w;
            #pragma unroll
            for (int j = 0; j < 4; ++j) w[j] = o1[g4 * 4 + j] * inv;
            *(f32x4*)(Out + orow + 32 + g4 * 8 + hi * 4) = w;
        }
    }
}

// ---------------- fallback (used only if ws too small) ----------------
__device__ __forceinline__ void load_tile_fb(const float* __restrict__ Kb,
                                             const float* __restrict__ Vb,
                                             int tid, f32x4 kv[4], f32x4 vv[4]) {
    #pragma unroll
    for (int h = 0; h < 4; ++h) {
        const int c = tid + h * 256;
        kv[h] = *(const f32x4*)(Kb + (c >> 4) * 64 + (c & 15) * 4);
    }
    #pragma unroll
    for (int h = 0; h < 2; ++h) {
        const int u  = tid + h * 256;
        const int d4 = (u & 3) + ((u >> 7) << 2);
        const int kp = (u >> 2) & 31;
        vv[2 * h]     = *(const f32x4*)(Vb + (2 * kp) * 64 + d4 * 4);
        vv[2 * h + 1] = *(const f32x4*)(Vb + (2 * kp + 1) * 64 + d4 * 4);
    }
}

__global__ __launch_bounds__(256, 4)
void attn_fb(const float* __restrict__ Qp, const float* __restrict__ Kp,
             const float* __restrict__ Vp, const int* __restrict__ meta,
             float* __restrict__ Out) {
    constexpr int S = SEQ;
    constexpr int qtiles = S >> 6;
    __shared__ short        lK [64 * KSTR];
    __shared__ unsigned int lVt[64 * VSTR];
    __shared__ unsigned int lPt[4 * 32 * PSTR];
    const int tid = threadIdx.x;
    const int wave = tid >> 6, lane = tid & 63;
    const int l15 = lane & 15, grp = lane >> 4;
    const int slot = blockIdx.x / qtiles, qt = blockIdx.x % qtiles;
    const int vl = meta[slot], batch = meta[BATCH + slot];
    const int ntiles = (vl + 63) >> 6;
    const float* Kb = Kp + (size_t)batch * S * 64;
    const float* Vb = Vp + (size_t)batch * S * 64;
    bf16x8 qf[2];
    {
        const float* qb = Qp + ((size_t)batch * S + qt * 64 + wave * 16 + l15) * 64 + grp * 8;
        #pragma unroll
        for (int kf = 0; kf < 2; ++kf) {
            f32x4 a = *(const f32x4*)(qb + kf * 32);
            f32x4 b = *(const f32x4*)(qb + kf * 32 + 4);
            union { bf16x8 v; unsigned int u[4]; } qq;
            qq.u[0] = pk2(a[0], a[1]); qq.u[1] = pk2(a[2], a[3]);
            qq.u[2] = pk2(b[0], b[1]); qq.u[3] = pk2(b[2], b[3]);
            qf[kf] = qq.v;
        }
    }
    f32x4 o[4] = {{0.f,0.f,0.f,0.f},{0.f,0.f,0.f,0.f},{0.f,0.f,0.f,0.f},{0.f,0.f,0.f,0.f}};
    float mrun = -INFINITY, lrun = 0.f;
    unsigned int* pw = &lPt[wave * 32 * PSTR];
    f32x4 kv[4], vv[4];
    if (ntiles > 0) load_tile_fb(Kb, Vb, tid, kv, vv);
    for (int kt = 0; kt < ntiles; ++kt) {
        const int kb = kt * 64;
        __syncthreads();
        #pragma unroll
        for (int h = 0; h < 4; ++h) {
            const int c = tid + h * 256;
            const int row = c >> 4, col = (c & 15) * 4;
            union { f32x4 f; float e[4]; } x; x.f = kv[h];
            unsigned int* dst = (unsigned int*)&lK[row * KSTR + col];
            dst[0] = pk2(x.e[0], x.e[1]); dst[1] = pk2(x.e[2], x.e[3]);
        }
        #pragma unroll
        for (int h = 0; h < 2; ++h) {
            const int u  = tid + h * 256;
            const int d4 = (u & 3) + ((u >> 7) << 2);
            const int kp = (u >> 2) & 31;
            union { f32x4 f; float e[4]; } a, b;
            a.f = vv[2 * h]; b.f = vv[2 * h + 1];
            #pragma unroll
            for (int j = 0; j < 4; ++j)
                lVt[(d4 * 4 + j) * VSTR + kp] = pk2(a.e[j], b.e[j]);
        }
        if (kt + 1 < ntiles) load_tile_fb(Kb + (size_t)(kb + 64) * 64, Vb + (size_t)(kb + 64) * 64, tid, kv, vv);
        __syncthreads();
        f32x4 st[4] = {{0.f,0.f,0.f,0.f},{0.f,0.f,0.f,0.f},{0.f,0.f,0.f,0.f},{0.f,0.f,0.f,0.f}};
        #pragma unroll
        for (int kf = 0; kf < 2; ++kf) {
            #pragma unroll
            for (int ct = 0; ct < 4; ++ct) {
                bf16x8 kfr = *(const bf16x8*)&lK[(ct * 16 + l15) * KSTR + kf * 32 + grp * 8];
                st[ct] = __builtin_amdgcn_mfma_f32_16x16x32_bf16(kfr, qf[kf], st[ct], 0, 0, 0);
            }
        }
        #pragma unroll
        for (int ct = 0; ct < 4; ++ct)
            #pragma unroll
            for (int r = 0; r < 4; ++r) {
                const bool valid = (kb + ct * 16 + grp * 4 + r) < vl;
                st[ct][r] = valid ? st[ct][r] * (0.125f * LOG2E) : NEGL;
            }
        float t0 = fmaxf(fmaxf(st[0][0], st[0][1]), fmaxf(st[0][2], st[0][3]));
        float t1 = fmaxf(fmaxf(st[1][0], st[1][1]), fmaxf(st[1][2], st[1][3]));
        float t2 = fmaxf(fmaxf(st[2][0], st[2][1]), fmaxf(st[2][2], st[2][3]));
        float t3 = fmaxf(fmaxf(st[3][0], st[3][1]), fmaxf(st[3][2], st[3][3]));
        float tm = fmaxf(fmaxf(t0, t1), fmaxf(t2, t3));
        tm = fmaxf(tm, __shfl_xor(tm, 16));
        tm = fmaxf(tm, __shfl_xor(tm, 32));
        const float mnew  = fmaxf(mrun, tm);
        const float alpha = exp2f(mrun - mnew);
        mrun = mnew;
        lrun *= alpha;
        #pragma unroll
        for (int dt = 0; dt < 4; ++dt)
            #pragma unroll
            for (int r = 0; r < 4; ++r) o[dt][r] *= alpha;
        float rs = 0.f;
        #pragma unroll
        for (int ct = 0; ct < 4; ++ct) {
            #pragma unroll
            for (int r = 0; r < 4; ++r) {
                st[ct][r] = exp2f(st[ct][r] - mrun);
                rs += st[ct][r];
            }
            #pragma unroll
            for (int a = 0; a < 2; ++a)
                pw[(ct * 8 + grp * 2 + a) * PSTR + l15] = pk2(st[ct][2 * a], st[ct][2 * a + 1]);
        }
        rs += __shfl_xor(rs, 16);
        rs += __shfl_xor(rs, 32);
        lrun += rs;
        asm volatile("s_waitcnt lgkmcnt(0)" ::: "memory");
        #pragma unroll
        for (int kk = 0; kk < 2; ++kk) {
            union { bf16x8 v; unsigned int u[4]; } pf;
            #pragma unroll
            for (int jj = 0; jj < 4; ++jj)
                pf.u[jj] = pw[(kk * 16 + grp * 4 + jj) * PSTR + l15];
            #pragma unroll
            for (int dt = 0; dt < 4; ++dt) {
                bf16x8 vf = *(const bf16x8*)&lVt[(dt * 16 + l15) * VSTR + kk * 16 + grp * 4];
                o[dt] = __builtin_amdgcn_mfma_f32_16x16x32_bf16(vf, pf.v, o[dt], 0, 0, 0);
            }
        }
    }
    const float inv = (lrun > 0.f) ? 1.0f / lrun : 0.f;
    const size_t orow = ((size_t)batch * S + qt * 64 + wave * 16 + l15) * 64;
    #pragma unroll
    for (int dt = 0; dt < 4; ++dt) {
        f32x4 w = o[dt];
        w[0] *= inv; w[1] *= inv; w[2] *= inv; w[3] *= inv;
        *(f32x4*)(Out + orow + dt * 16 + grp * 4) = w;
    }
}

extern "C" void kernel_launch(void* const* d_in, const int* in_sizes, int n_in,
                              void* d_out, int out_size, void* d_ws, size_t ws_size,
                              hipStream_t stream) {
    const float* Q  = (const float*)d_in[0];
    const float* K  = (const float*)d_in[1];
    const float* V  = (const float*)d_in[2];
    const int*   VL = (const int*)d_in[3];
    int* meta = (int*)d_ws;                    // 64 ints
    const size_t need = 512 + 2 * (size_t)BATCH * SEQ * 64 * sizeof(short);  // ~16.8 MB
    if (ws_size >= need) {
        short* Kw = (short*)((char*)d_ws + 512);
        short* Vw = Kw + (size_t)BATCH * SEQ * 64;
        prepkv<<<dim3(BATCH * 32 + 1), dim3(256), 0, stream>>>(K, V, VL, Kw, Vw, meta);
        attn_fwd<<<dim3(BATCH * 32), dim3(512), 0, stream>>>(Q, Kw, Vw, meta, (float*)d_out);
    } else {
        prep_vl<<<1, 64, 0, stream>>>(VL, meta);
        attn_fb<<<dim3(BATCH * (SEQ >> 6)), dim3(256), 0, stream>>>(Q, K, V, meta, (float*)d_out);
    }
}

// Round 12
// 119.252 us; speedup vs baseline: 1.5547x; 1.5547x over previous
//
#include <hip/hip_runtime.h>
#include <hip/hip_bf16.h>

typedef __attribute__((ext_vector_type(8))) short bf16x8;
typedef __attribute__((ext_vector_type(4))) float f32x4;
typedef __attribute__((ext_vector_type(16))) float f32x16;
typedef __attribute__((ext_vector_type(4))) unsigned int u32x4;

#define BATCH 32
#define SEQ   2048
#define PSTR  20    // fallback kernel only
#define KSTR  72    // fallback kernel only
#define VSTR  36    // fallback + prepkv staging
#define LOG2E 1.44269504088896340736f
#define QSCALE (0.125f * LOG2E)
#define NEGL  (-1000000.0f * LOG2E)

__device__ __forceinline__ unsigned int pk2(float lo, float hi) {
    __hip_bfloat162 h2 = __float22bfloat162_rn(make_float2(lo, hi));  // v_cvt_pk_bf16_f32
    return *reinterpret_cast<unsigned int*>(&h2);
}

// v_permlane32_swap_b32: a[32:63] <-> b[0:31].
__device__ __forceinline__ void plswap(unsigned int& a, unsigned int& b) {
    asm volatile("v_permlane32_swap_b32 %0, %1" : "+v"(a), "+v"(b));
}

// standalone prep (fallback path only)
__global__ void prep_vl(const int* __restrict__ VL, int* __restrict__ meta) {
    __shared__ int sv[BATCH];
    const int t = threadIdx.x;
    int odd = (t < 16) ? VL[2 * t + 1] : 0;
    const bool is64 = (__ballot(odd != 0) == 0ULL);
    if (t < BATCH) {
        int x = is64 ? VL[2 * t] : VL[t];
        x = x < 0 ? 0 : (x > SEQ ? SEQ : x);
        sv[t] = x;
    }
    __syncthreads();
    if (t < BATCH) {
        const int x = sv[t];
        int rank = 0;
        for (int j = 0; j < BATCH; ++j) {
            const int y = sv[j];
            rank += (y > x) || (y == x && j < t);
        }
        meta[rank] = x;
        meta[BATCH + rank] = t;
    }
}

// FRAGMENT-MAJOR workspace (r7, verified). Each MFMA fragment of attn is a
// contiguous lane-ordered 1KB extent. Linear in the 32-key group G:
//   Kw byte off = (b*64 + G)*4096 + kf*1024 + lane*16
//   Vw byte off = (b*64 + G)*4096 + q*1024  + lane*16
// -> attn loads each fragment with ONE coalesced global_load_dwordx4,
// enabling a barrier-free main loop with any key partition across waves.
// Tiles beyond ceil64(vl[b]) are skipped. Block BATCH*32 does the rank-sort.
__global__ __launch_bounds__(256) void prepkv(const float* __restrict__ Kp,
                                              const float* __restrict__ Vp,
                                              const int* __restrict__ VL,
                                              short* __restrict__ Kw,
                                              short* __restrict__ Vw,
                                              int* __restrict__ meta) {
    __shared__ unsigned int l[64 * VSTR];
    __shared__ int sv[BATCH];
    __shared__ int svl;
    const int tid = threadIdx.x;
    if (blockIdx.x == BATCH * 32) {
        if (tid < 64) {
            int odd = (tid < 16) ? VL[2 * tid + 1] : 0;
            const bool is64 = (__ballot(odd != 0) == 0ULL);   // lens>=1
            if (tid < BATCH) {
                int x = is64 ? VL[2 * tid] : VL[tid];
                x = x < 0 ? 0 : (x > SEQ ? SEQ : x);
                sv[tid] = x;
            }
            asm volatile("s_waitcnt lgkmcnt(0)" ::: "memory");
            if (tid < BATCH) {
                const int x = sv[tid];
                int rank = 0;
                for (int j = 0; j < BATCH; ++j) {
                    const int y = sv[j];
                    rank += (y > x) || (y == x && j < tid);
                }
                meta[rank] = x;
                meta[BATCH + rank] = tid;
            }
        }
        return;
    }
    const int b = blockIdx.x >> 5, kt = blockIdx.x & 31, kb = kt * 64;
    // per-block vl: skip tiles attn never reads (kt*64 >= ceil64(vl))
    if (tid < 64) {
        int odd = (tid < 16) ? VL[2 * tid + 1] : 0;
        const bool is64 = (__ballot(odd != 0) == 0ULL);
        if (tid == 0) {
            int x = is64 ? VL[2 * b] : VL[b];
            x = x < 0 ? 0 : (x > SEQ ? SEQ : x);
            svl = x;
        }
    }
    __syncthreads();
    if (kb >= ((svl + 63) & ~63)) return;   // block-uniform exit
    const float* Kv = Kp + ((size_t)b * SEQ + kb) * 64;
    const float* Vb = Vp + ((size_t)b * SEQ + kb) * 64;
    const size_t tbase = (size_t)(b * 32 + kt) * 8192;   // bytes per tile

    // K: 512 chunks of 16B, fragment-major; writes coalesced
    #pragma unroll
    for (int h = 0; h < 2; ++h) {
        const int c = tid + h * 256;
        const int kh = c >> 8, kf = (c >> 6) & 3, ln = c & 63;
        const int key = kh * 32 + (ln & 31), col = kf * 16 + (ln >> 5) * 8;
        f32x4 a = *(const f32x4*)(Kv + key * 64 + col);
        f32x4 d = *(const f32x4*)(Kv + key * 64 + col + 4);
        u32x4 w;
        w.x = pk2(a[0], a[1]); w.y = pk2(a[2], a[3]);
        w.z = pk2(d[0], d[1]); w.w = pk2(d[2], d[3]);
        *(u32x4*)((char*)Kw + tbase + (size_t)c * 16) = w;
    }
    // V: build packed-pair transpose in LDS, then fragment-major out
    #pragma unroll
    for (int h = 0; h < 2; ++h) {
        const int u = tid + h * 256;
        const int d4 = (u & 3) + ((u >> 7) << 2);
        const int kp = (u >> 2) & 31;
        f32x4 a = *(const f32x4*)(Vb + (2 * kp) * 64 + d4 * 4);
        f32x4 c = *(const f32x4*)(Vb + (2 * kp + 1) * 64 + d4 * 4);
        #pragma unroll
        for (int j = 0; j < 4; ++j)
            l[(d4 * 4 + j) * VSTR + kp] = pk2(a[j], c[j]);
    }
    __syncthreads();
    #pragma unroll
    for (int h = 0; h < 2; ++h) {
        const int cV = tid + h * 256;
        const int kh = cV >> 8, q = (cV >> 6) & 3, ln = cV & 63;
        const int d = (q >> 1) * 32 + (ln & 31);
        const int cc = kh * 4 + (q & 1) * 2 + (ln >> 5);
        u32x4 w = *(const u32x4*)&l[d * VSTR + 4 * cc];
        *(u32x4*)((char*)Vw + tbase + (size_t)cV * 16) = w;
    }
}

// ---- main: round-12 = r10 loop with Q-FATTENED waves (64 q-rows/wave).
// r11 post-mortem: depth-2 prefetch SPILLED (accumulators live in AGPRs ->
// each wave already ~128 total regs; +64 VGPR blew the budget, 250MB scratch).
// Real constraint exposed: ~4 waves/SIMD cap, and per-tile load-latency
// exposure is the surviving stall theory. This round halves the number of
// load events per unit work WITHOUT prefetch registers: each wave's K/V
// fragments feed TWO q-sets (A = rows 0-31, B = rows 32-63 of the 64-q tile)
// -> per tile 8KB loads / 16 MFMAs (was 8), total fragment loads 541k->270k,
// and per-tile issue (~500cyc) now covers depth-1 load latency. Block = 256
// thr = 4 kh-waves sharing one 64-q tile; __launch_bounds__(256,2) gives a
// 256-reg budget (need ~190: no spill -- r8/r11 failed by SHRINKING budget).
// XCD-affine decode kept (r10: FETCH at compulsory 12.5MB). Barrier-free
// loop; 4-way kh merge over both q-sets at the end. ----
__global__ __launch_bounds__(256, 2)
void attn_fwd(const float* __restrict__ Qp, const short* __restrict__ Kw,
              const short* __restrict__ Vw, const int* __restrict__ meta,
              float* __restrict__ Out) {
    constexpr int S = SEQ;
    __shared__ float mA[4 * 1024];   // 16 KB: [set 4][reg 16][lane 64]
    __shared__ float mB[4 * 1024];   // 16 KB
    __shared__ float lA[128], lB[128];

    const int tid  = threadIdx.x;
    const int kh   = tid >> 6;        // wave = key-quarter (mod-4 groups)
    const int lane = tid & 63;
    const int r31 = lane & 31, hi = lane >> 5;

    // XCD-affine decode: x = XCD (blockIdx%8 round-robin); XCD x owns slots
    // {x,15-x,16+x,31-x} (balanced rank sums); all 32 qt-blocks of a slot
    // share one XCD -> per-XCD working set 2MB <= 4MB L2 (r10: FETCH 12.5MB).
    const int x  = blockIdx.x & 7;
    const int i  = blockIdx.x >> 3;
    const int ss = i >> 5;
    const int qt = i & 31;
    const int slot = (ss == 0) ? x : (ss == 1) ? 15 - x : (ss == 2) ? 16 + x : 31 - x;

    const int vl = meta[slot], batch = meta[BATCH + slot];
    const int nG = (vl + 31) >> 5;                         // 32-key groups
    const int ntw = (nG > kh) ? ((nG - kh + 3) >> 2) : 0;  // this wave's groups

    // fragment base pointers: group G at byte (batch*64+G)*4096; step 16384
    const char* kw = (const char*)Kw + ((size_t)batch * 64 + kh) * 4096 + lane * 16;
    const char* vw = (const char*)Vw + ((size_t)batch * 64 + kh) * 4096 + lane * 16;

    // Q B-fragments for BOTH 32-row sets of this block's 64-q tile
    // (lane holds Q[qset*32+r31][kf*16+hi*8+j], scale folded -> log2 domain)
    bf16x8 qfA[4], qfB[4];
    {
        const float* qa = Qp + ((size_t)batch * S + qt * 64 + r31) * 64 + hi * 8;
        const float* qb = qa + 32 * 64;
        #pragma unroll
        for (int kf = 0; kf < 4; ++kf) {
            f32x4 a = *(const f32x4*)(qa + kf * 16);
            f32x4 c = *(const f32x4*)(qa + kf * 16 + 4);
            union { bf16x8 v; unsigned int u[4]; } qq;
            qq.u[0] = pk2(a[0] * QSCALE, a[1] * QSCALE);
            qq.u[1] = pk2(a[2] * QSCALE, a[3] * QSCALE);
            qq.u[2] = pk2(c[0] * QSCALE, c[1] * QSCALE);
            qq.u[3] = pk2(c[2] * QSCALE, c[3] * QSCALE);
            qfA[kf] = qq.v;
            f32x4 e = *(const f32x4*)(qb + kf * 16);
            f32x4 f = *(const f32x4*)(qb + kf * 16 + 4);
            qq.u[0] = pk2(e[0] * QSCALE, e[1] * QSCALE);
            qq.u[1] = pk2(e[2] * QSCALE, e[3] * QSCALE);
            qq.u[2] = pk2(f[0] * QSCALE, f[1] * QSCALE);
            qq.u[3] = pk2(f[2] * QSCALE, f[3] * QSCALE);
            qfB[kf] = qq.v;
        }
    }

    f32x16 oA0, oA1, oB0, oB1, zv;
    #pragma unroll
    for (int r = 0; r < 16; ++r) {
        oA0[r] = 0.f; oA1[r] = 0.f; oB0[r] = 0.f; oB1[r] = 0.f; zv[r] = 0.f;
    }
    float lpA = 0.f, lpB = 0.f;

    bf16x8 kk0, kk1, kk2, kk3, vv0, vv1, vv2, vv3;
    if (ntw > 0) {
        kk0 = *(const bf16x8*)(kw);
        kk1 = *(const bf16x8*)(kw + 1024);
        kk2 = *(const bf16x8*)(kw + 2048);
        kk3 = *(const bf16x8*)(kw + 3072);
        vv0 = *(const bf16x8*)(vw);
        vv1 = *(const bf16x8*)(vw + 1024);
        vv2 = *(const bf16x8*)(vw + 2048);
        vv3 = *(const bf16x8*)(vw + 3072);
    }

    for (int t = 0; t < ntw; ++t) {
        // QK for both q-sets: K fragments consumed by 8 MFMAs (one load set)
        f32x16 sA, sB;
        __builtin_amdgcn_s_setprio(1);
        sA = __builtin_amdgcn_mfma_f32_32x32x16_bf16(kk0, qfA[0], zv, 0, 0, 0);
        sB = __builtin_amdgcn_mfma_f32_32x32x16_bf16(kk0, qfB[0], zv, 0, 0, 0);
        sA = __builtin_amdgcn_mfma_f32_32x32x16_bf16(kk1, qfA[1], sA, 0, 0, 0);
        sB = __builtin_amdgcn_mfma_f32_32x32x16_bf16(kk1, qfB[1], sB, 0, 0, 0);
        sA = __builtin_amdgcn_mfma_f32_32x32x16_bf16(kk2, qfA[2], sA, 0, 0, 0);
        sB = __builtin_amdgcn_mfma_f32_32x32x16_bf16(kk2, qfB[2], sB, 0, 0, 0);
        sA = __builtin_amdgcn_mfma_f32_32x32x16_bf16(kk3, qfA[3], sA, 0, 0, 0);
        sB = __builtin_amdgcn_mfma_f32_32x32x16_bf16(kk3, qfB[3], sB, 0, 0, 0);
        __builtin_amdgcn_s_setprio(0);

        // K prefetch t+1 (k regs dead after the cluster above)
        if (t + 1 < ntw) {
            const char* p = kw + (size_t)(t + 1) * 16384;
            kk0 = *(const bf16x8*)(p);
            kk1 = *(const bf16x8*)(p + 1024);
            kk2 = *(const bf16x8*)(p + 2048);
            kk3 = *(const bf16x8*)(p + 3072);
        }

        // mask the last partial 32-key group (keys only -> same for A and B)
        const int rem = vl - (kh + 4 * t) * 32;
        if (rem < 32) {
            #pragma unroll
            for (int r = 0; r < 16; ++r) {
                const int kl = 4 * hi + (r & 3) + 8 * (r >> 2);
                const bool v = (kl < rem);
                sA[r] = v ? sA[r] : NEGL;
                sB[r] = v ? sB[r] : NEGL;
            }
        }

        // p = exp2(s') (no max subtraction; masked -> exactly 0)
        #pragma unroll
        for (int r = 0; r < 16; ++r) {
            sA[r] = __builtin_amdgcn_exp2f(sA[r]);
            sB[r] = __builtin_amdgcn_exp2f(sB[r]);
        }
        {
            const float a0 = (sA[0] + sA[1]) + (sA[2] + sA[3]);
            const float a1 = (sA[4] + sA[5]) + (sA[6] + sA[7]);
            const float a2 = (sA[8] + sA[9]) + (sA[10] + sA[11]);
            const float a3 = (sA[12] + sA[13]) + (sA[14] + sA[15]);
            lpA += (a0 + a1) + (a2 + a3);
            const float b0 = (sB[0] + sB[1]) + (sB[2] + sB[3]);
            const float b1 = (sB[4] + sB[5]) + (sB[6] + sB[7]);
            const float b2 = (sB[8] + sB[9]) + (sB[10] + sB[11]);
            const float b3 = (sB[12] + sB[13]) + (sB[14] + sB[15]);
            lpB += (b0 + b1) + (b2 + b3);
        }

        // in-register P^T -> PV B-fragments (T12), both q-sets
        union { bf16x8 v; unsigned int u[4]; } pA0, pA1, pB0, pB1;
        {
            unsigned int x0 = pk2(sA[0], sA[1]),   y0 = pk2(sA[4], sA[5]);
            unsigned int x1 = pk2(sA[2], sA[3]),   y1 = pk2(sA[6], sA[7]);
            plswap(x0, y0); plswap(x1, y1);
            pA0.u[0] = x0; pA0.u[1] = x1; pA0.u[2] = y0; pA0.u[3] = y1;
            unsigned int x2 = pk2(sA[8], sA[9]),   y2 = pk2(sA[12], sA[13]);
            unsigned int x3 = pk2(sA[10], sA[11]), y3 = pk2(sA[14], sA[15]);
            plswap(x2, y2); plswap(x3, y3);
            pA1.u[0] = x2; pA1.u[1] = x3; pA1.u[2] = y2; pA1.u[3] = y3;
            unsigned int z0 = pk2(sB[0], sB[1]),   w0 = pk2(sB[4], sB[5]);
            unsigned int z1 = pk2(sB[2], sB[3]),   w1 = pk2(sB[6], sB[7]);
            plswap(z0, w0); plswap(z1, w1);
            pB0.u[0] = z0; pB0.u[1] = z1; pB0.u[2] = w0; pB0.u[3] = w1;
            unsigned int z2 = pk2(sB[8], sB[9]),   w2 = pk2(sB[12], sB[13]);
            unsigned int z3 = pk2(sB[10], sB[11]), w3 = pk2(sB[14], sB[15]);
            plswap(z2, w2); plswap(z3, w3);
            pB1.u[0] = z2; pB1.u[1] = z3; pB1.u[2] = w2; pB1.u[3] = w3;
        }

        // PV for both q-sets: V fragments consumed by 8 MFMAs (one load set)
        __builtin_amdgcn_s_setprio(1);
        oA0 = __builtin_amdgcn_mfma_f32_32x32x16_bf16(vv0, pA0.v, oA0, 0, 0, 0);
        oB0 = __builtin_amdgcn_mfma_f32_32x32x16_bf16(vv0, pB0.v, oB0, 0, 0, 0);
        oA0 = __builtin_amdgcn_mfma_f32_32x32x16_bf16(vv1, pA1.v, oA0, 0, 0, 0);
        oB0 = __builtin_amdgcn_mfma_f32_32x32x16_bf16(vv1, pB1.v, oB0, 0, 0, 0);
        oA1 = __builtin_amdgcn_mfma_f32_32x32x16_bf16(vv2, pA0.v, oA1, 0, 0, 0);
        oB1 = __builtin_amdgcn_mfma_f32_32x32x16_bf16(vv2, pB0.v, oB1, 0, 0, 0);
        oA1 = __builtin_amdgcn_mfma_f32_32x32x16_bf16(vv3, pA1.v, oA1, 0, 0, 0);
        oB1 = __builtin_amdgcn_mfma_f32_32x32x16_bf16(vv3, pB1.v, oB1, 0, 0, 0);
        __builtin_amdgcn_s_setprio(0);

        // V prefetch t+1
        if (t + 1 < ntw) {
            const char* p = vw + (size_t)(t + 1) * 16384;
            vv0 = *(const bf16x8*)(p);
            vv1 = *(const bf16x8*)(p + 1024);
            vv2 = *(const bf16x8*)(p + 2048);
            vv3 = *(const bf16x8*)(p + 3072);
        }
    }

    // per-(q, key-quarter) l: lanes l and l+32 hold complementary row sets
    float lwA = lpA + __shfl_xor(lpA, 32);
    float lwB = lpB + __shfl_xor(lpB, 32);

    // 4-way kh merge: (1,3 -> A,B) -> (0+=A, 2+=B) -> (2 -> A) -> (0+=A)
    if (kh == 1 || kh == 3) {
        float* m  = (kh == 1) ? mA : mB;
        float* lv = (kh == 1) ? lA : lB;
        #pragma unroll
        for (int r = 0; r < 16; ++r) {
            m[0 * 1024 + r * 64 + lane] = oA0[r];
            m[1 * 1024 + r * 64 + lane] = oA1[r];
            m[2 * 1024 + r * 64 + lane] = oB0[r];
            m[3 * 1024 + r * 64 + lane] = oB1[r];
        }
        lv[lane] = lwA; lv[64 + lane] = lwB;
    }
    __syncthreads();
    if (kh == 0 || kh == 2) {
        const float* m  = (kh == 0) ? mA : mB;
        const float* lv = (kh == 0) ? lA : lB;
        #pragma unroll
        for (int r = 0; r < 16; ++r) {
            oA0[r] += m[0 * 1024 + r * 64 + lane];
            oA1[r] += m[1 * 1024 + r * 64 + lane];
            oB0[r] += m[2 * 1024 + r * 64 + lane];
            oB1[r] += m[3 * 1024 + r * 64 + lane];
        }
        lwA += lv[lane]; lwB += lv[64 + lane];
    }
    __syncthreads();
    if (kh == 2) {
        #pragma unroll
        for (int r = 0; r < 16; ++r) {
            mA[0 * 1024 + r * 64 + lane] = oA0[r];
            mA[1 * 1024 + r * 64 + lane] = oA1[r];
            mA[2 * 1024 + r * 64 + lane] = oB0[r];
            mA[3 * 1024 + r * 64 + lane] = oB1[r];
        }
        lA[lane] = lwA; lA[64 + lane] = lwB;
    }
    __syncthreads();
    if (kh == 0) {
        #pragma unroll
        for (int r = 0; r < 16; ++r) {
            oA0[r] += mA[0 * 1024 + r * 64 + lane];
            oA1[r] += mA[1 * 1024 + r * 64 + lane];
            oB0[r] += mA[2 * 1024 + r * 64 + lane];
            oB1[r] += mA[3 * 1024 + r * 64 + lane];
        }
        lwA += lA[lane]; lwB += lA[64 + lane];
        const float invA = (lwA > 0.f) ? 1.0f / lwA : 0.f;
        const float invB = (lwB > 0.f) ? 1.0f / lwB : 0.f;
        const size_t orowA = ((size_t)batch * S + qt * 64 + r31) * 64;
        const size_t orowB = orowA + (size_t)32 * 64;
        #pragma unroll
        for (int g4 = 0; g4 < 4; ++g4) {
            f32x4 w;
            #pragma unroll
            for (int j = 0; j < 4; ++j) w[j] = oA0[g4 * 4 + j] * invA;
            *(f32x4*)(Out + orowA + g4 * 8 + hi * 4) = w;
            #pragma unroll
            for (int j = 0; j < 4; ++j) w[j] = oA1[g4 * 4 + j] * invA;
            *(f32x4*)(Out + orowA + 32 + g4 * 8 + hi * 4) = w;
            #pragma unroll
            for (int j = 0; j < 4; ++j) w[j] = oB0[g4 * 4 + j] * invB;
            *(f32x4*)(Out + orowB + g4 * 8 + hi * 4) = w;
            #pragma unroll
            for (int j = 0; j < 4; ++j) w[j] = oB1[g4 * 4 + j] * invB;
            *(f32x4*)(Out + orowB + 32 + g4 * 8 + hi * 4) = w;
        }
    }
}

// ---------------- fallback (used only if ws too small) ----------------
__device__ __forceinline__ void load_tile_fb(const float* __restrict__ Kb,
                                             const float* __restrict__ Vb,
                                             int tid, f32x4 kv[4], f32x4 vv[4]) {
    #pragma unroll
    for (int h = 0; h < 4; ++h) {
        const int c = tid + h * 256;
        kv[h] = *(const f32x4*)(Kb + (c >> 4) * 64 + (c & 15) * 4);
    }
    #pragma unroll
    for (int h = 0; h < 2; ++h) {
        const int u  = tid + h * 256;
        const int d4 = (u & 3) + ((u >> 7) << 2);
        const int kp = (u >> 2) & 31;
        vv[2 * h]     = *(const f32x4*)(Vb + (2 * kp) * 64 + d4 * 4);
        vv[2 * h + 1] = *(const f32x4*)(Vb + (2 * kp + 1) * 64 + d4 * 4);
    }
}

__global__ __launch_bounds__(256, 4)
void attn_fb(const float* __restrict__ Qp, const float* __restrict__ Kp,
             const float* __restrict__ Vp, const int* __restrict__ meta,
             float* __restrict__ Out) {
    constexpr int S = SEQ;
    constexpr int qtiles = S >> 6;
    __shared__ short        lK [64 * KSTR];
    __shared__ unsigned int lVt[64 * VSTR];
    __shared__ unsigned int lPt[4 * 32 * PSTR];
    const int tid = threadIdx.x;
    const int wave = tid >> 6, lane = tid & 63;
    const int l15 = lane & 15, grp = lane >> 4;
    const int slot = blockIdx.x / qtiles, qt = blockIdx.x % qtiles;
    const int vl = meta[slot], batch = meta[BATCH + slot];
    const int ntiles = (vl + 63) >> 6;
    const float* Kb = Kp + (size_t)batch * S * 64;
    const float* Vb = Vp + (size_t)batch * S * 64;
    bf16x8 qf[2];
    {
        const float* qb = Qp + ((size_t)batch * S + qt * 64 + wave * 16 + l15) * 64 + grp * 8;
        #pragma unroll
        for (int kf = 0; kf < 2; ++kf) {
            f32x4 a = *(const f32x4*)(qb + kf * 32);
            f32x4 b = *(const f32x4*)(qb + kf * 32 + 4);
            union { bf16x8 v; unsigned int u[4]; } qq;
            qq.u[0] = pk2(a[0], a[1]); qq.u[1] = pk2(a[2], a[3]);
            qq.u[2] = pk2(b[0], b[1]); qq.u[3] = pk2(b[2], b[3]);
            qf[kf] = qq.v;
        }
    }
    f32x4 o[4] = {{0.f,0.f,0.f,0.f},{0.f,0.f,0.f,0.f},{0.f,0.f,0.f,0.f},{0.f,0.f,0.f,0.f}};
    float mrun = -INFINITY, lrun = 0.f;
    unsigned int* pw = &lPt[wave * 32 * PSTR];
    f32x4 kv[4], vv[4];
    if (ntiles > 0) load_tile_fb(Kb, Vb, tid, kv, vv);
    for (int kt = 0; kt < ntiles; ++kt) {
        const int kb = kt * 64;
        __syncthreads();
        #pragma unroll
        for (int h = 0; h < 4; ++h) {
            const int c = tid + h * 256;
            const int row = c >> 4, col = (c & 15) * 4;
            union { f32x4 f; float e[4]; } x; x.f = kv[h];
            unsigned int* dst = (unsigned int*)&lK[row * KSTR + col];
            dst[0] = pk2(x.e[0], x.e[1]); dst[1] = pk2(x.e[2], x.e[3]);
        }
        #pragma unroll
        for (int h = 0; h < 2; ++h) {
            const int u  = tid + h * 256;
            const int d4 = (u & 3) + ((u >> 7) << 2);
            const int kp = (u >> 2) & 31;
            union { f32x4 f; float e[4]; } a, b;
            a.f = vv[2 * h]; b.f = vv[2 * h + 1];
            #pragma unroll
            for (int j = 0; j < 4; ++j)
                lVt[(d4 * 4 + j) * VSTR + kp] = pk2(a.e[j], b.e[j]);
        }
        if (kt + 1 < ntiles) load_tile_fb(Kb + (size_t)(kb + 64) * 64, Vb + (size_t)(kb + 64) * 64, tid, kv, vv);
        __syncthreads();
        f32x4 st[4] = {{0.f,0.f,0.f,0.f},{0.f,0.f,0.f,0.f},{0.f,0.f,0.f,0.f},{0.f,0.f,0.f,0.f}};
        #pragma unroll
        for (int kf = 0; kf < 2; ++kf) {
            #pragma unroll
            for (int ct = 0; ct < 4; ++ct) {
                bf16x8 kfr = *(const bf16x8*)&lK[(ct * 16 + l15) * KSTR + kf * 32 + grp * 8];
                st[ct] = __builtin_amdgcn_mfma_f32_16x16x32_bf16(kfr, qf[kf], st[ct], 0, 0, 0);
            }
        }
        #pragma unroll
        for (int ct = 0; ct < 4; ++ct)
            #pragma unroll
            for (int r = 0; r < 4; ++r) {
                const bool valid = (kb + ct * 16 + grp * 4 + r) < vl;
                st[ct][r] = valid ? st[ct][r] * (0.125f * LOG2E) : NEGL;
            }
        float t0 = fmaxf(fmaxf(st[0][0], st[0][1]), fmaxf(st[0][2], st[0][3]));
        float t1 = fmaxf(fmaxf(st[1][0], st[1][1]), fmaxf(st[1][2], st[1][3]));
        float t2 = fmaxf(fmaxf(st[2][0], st[2][1]), fmaxf(st[2][2], st[2][3]));
        float t3 = fmaxf(fmaxf(st[3][0], st[3][1]), fmaxf(st[3][2], st[3][3]));
        float tm = fmaxf(fmaxf(t0, t1), fmaxf(t2, t3));
        tm = fmaxf(tm, __shfl_xor(tm, 16));
        tm = fmaxf(tm, __shfl_xor(tm, 32));
        const float mnew  = fmaxf(mrun, tm);
        const float alpha = exp2f(mrun - mnew);
        mrun = mnew;
        lrun *= alpha;
        #pragma unroll
        for (int dt = 0; dt < 4; ++dt)
            #pragma unroll
            for (int r = 0; r < 4; ++r) o[dt][r] *= alpha;
        float rs = 0.f;
        #pragma unroll
        for (int ct = 0; ct < 4; ++ct) {
            #pragma unroll
            for (int r = 0; r < 4; ++r) {
                st[ct][r] = exp2f(st[ct][r] - mrun);
                rs += st[ct][r];
            }
            #pragma unroll
            for (int a = 0; a < 2; ++a)
                pw[(ct * 8 + grp * 2 + a) * PSTR + l15] = pk2(st[ct][2 * a], st[ct][2 * a + 1]);
        }
        rs += __shfl_xor(rs, 16);
        rs += __shfl_xor(rs, 32);
        lrun += rs;
        asm volatile("s_waitcnt lgkmcnt(0)" ::: "memory");
        #pragma unroll
        for (int kk = 0; kk < 2; ++kk) {
            union { bf16x8 v; unsigned int u[4]; } pf;
            #pragma unroll
            for (int jj = 0; jj < 4; ++jj)
                pf.u[jj] = pw[(kk * 16 + grp * 4 + jj) * PSTR + l15];
            #pragma unroll
            for (int dt = 0; dt < 4; ++dt) {
                bf16x8 vf = *(const bf16x8*)&lVt[(dt * 16 + l15) * VSTR + kk * 16 + grp * 4];
                o[dt] = __builtin_amdgcn_mfma_f32_16x16x32_bf16(vf, pf.v, o[dt], 0, 0, 0);
            }
        }
    }
    const float inv = (lrun > 0.f) ? 1.0f / lrun : 0.f;
    const size_t orow = ((size_t)batch * S + qt * 64 + wave * 16 + l15) * 64;
    #pragma unroll
    for (int dt = 0; dt < 4; ++dt) {
        f32x4 w = o[dt];
        w[0] *= inv; w[1] *= inv; w[2] *= inv; w[3] *= inv;
        *(f32x4*)(Out + orow + dt * 16 + grp * 4) = w;
    }
}

extern "C" void kernel_launch(void* const* d_in, const int* in_sizes, int n_in,
                              void* d_out, int out_size, void* d_ws, size_t ws_size,
                              hipStream_t stream) {
    const float* Q  = (const float*)d_in[0];
    const float* K  = (const float*)d_in[1];
    const float* V  = (const float*)d_in[2];
    const int*   VL = (const int*)d_in[3];
    int* meta = (int*)d_ws;                    // 64 ints
    const size_t need = 512 + 2 * (size_t)BATCH * SEQ * 64 * sizeof(short);  // ~16.8 MB
    if (ws_size >= need) {
        short* Kw = (short*)((char*)d_ws + 512);
        short* Vw = Kw + (size_t)BATCH * SEQ * 64;
        prepkv<<<dim3(BATCH * 32 + 1), dim3(256), 0, stream>>>(K, V, VL, Kw, Vw, meta);
        attn_fwd<<<dim3(BATCH * 32), dim3(256), 0, stream>>>(Q, Kw, Vw, meta, (float*)d_out);
    } else {
        prep_vl<<<1, 64, 0, stream>>>(VL, meta);
        attn_fb<<<dim3(BATCH * (SEQ >> 6)), dim3(256), 0, stream>>>(Q, K, V, meta, (float*)d_out);
    }
}